// Round 1
// baseline (1517.035 us; speedup 1.0000x reference)
//
#include <hip/hip_runtime.h>
#include <stdint.h>
#include <math.h>

#define BB 4
#define TT_ 1024
#define VV 32000
#define ANS 512
#define TOPK 50
#define IGN (-100)
#define NR (BB*ANS)              // 2048 rows per tensor
#define NGRP 4                   // colsum row groups (== BB)
#define RPG (NR/NGRP)            // 512 rows per group
#define NCHUNK (VV/256)          // 125 column chunks

// ---- workspace layout (float offsets) ----
#define WS_META   0                               // 16 ints
#define WS_STATS  32                              // [2][NR][4] = 16384 floats {scale, max*scale, 1/sumexp, srcrow(or -1)}
#define WS_CPART  (WS_STATS + 2*NR*4)             // [2][NGRP][VV] = 256000
#define WS_CSUM   (WS_CPART + 2*NGRP*VV)          // [2][VV] = 64000 (unused scratch)
#define WS_ORDER  (WS_CSUM + 2*VV)                // [2][64] ints (128 float slots)
#define WS_GAT    (WS_ORDER + 128)                // [2][BB][ANS][TOPK] = 204800
#define WS_W      (WS_GAT + 2*BB*ANS*TOPK)        // [BB][ANS][ANS] = 1048576
#define WS_K      (WS_W + BB*ANS*ANS)             // [BB][ANS][ANS]
#define WS_U      (WS_K + BB*ANS*ANS)             // [BB][ANS]
#define WS_V      (WS_U + BB*ANS)                 // [BB][ANS]
#define WS_LOSSP  (WS_V + BB*ANS)                 // [32]

// ---------------------------------------------------------------- answers
__global__ void answers_k(const int* st, const int* tt, float* ws) {
    int t = blockIdx.x >> 2, b = blockIdx.x & 3;
    const int* tg = (t == 0 ? st : tt) + b * TT_;
    __shared__ int smin[256], scnt[256];
    int mn = TT_, cnt = 0;
    for (int i = threadIdx.x; i < TT_; i += 256) {
        if (tg[i] != IGN) { cnt++; if (i < mn) mn = i; }
    }
    smin[threadIdx.x] = mn; scnt[threadIdx.x] = cnt;
    __syncthreads();
    for (int s = 128; s > 0; s >>= 1) {
        if (threadIdx.x < s) {
            smin[threadIdx.x] = min(smin[threadIdx.x], smin[threadIdx.x + s]);
            scnt[threadIdx.x] += scnt[threadIdx.x + s];
        }
        __syncthreads();
    }
    if (threadIdx.x == 0) {
        int* meta = (int*)ws;
        meta[t*8 + b]     = (scnt[0] == 0) ? 0 : smin[0];
        meta[t*8 + 4 + b] = scnt[0];
    }
}

// ------------------------------------------------- per-row stats + sumexp
__global__ void rowstats_k(const float* sl, const float* tl, float* ws) {
    int gid = blockIdx.x;
    int t = gid >> 11, r = gid & (NR - 1);
    int b = r >> 9, pos = r & (ANS - 1);
    const int* meta = (const int*)ws;
    int start = meta[t*8 + b], size = meta[t*8 + 4 + b];
    float* stp = ws + WS_STATS + (size_t)(t*NR + r) * 4;
    if (pos >= size) {
        if (threadIdx.x == 0) { stp[0] = 0.f; stp[1] = 0.f; stp[2] = 0.f; stp[3] = -1.f; }
        return;
    }
    int idx = start + pos; if (idx > TT_ - 1) idx = TT_ - 1;
    const float* x = (t == 0 ? sl : tl) + ((size_t)b * TT_ + idx) * (size_t)VV;
    const float4* x4 = (const float4*)x;   // 8000 float4s, row base is 16B aligned

    double s = 0.0, s2 = 0.0; float mx = -INFINITY;
    for (int q = threadIdx.x; q < VV/4; q += 256) {
        float4 v = x4[q];
        s  += (double)v.x + (double)v.y + (double)v.z + (double)v.w;
        s2 += (double)v.x*v.x + (double)v.y*v.y + (double)v.z*v.z + (double)v.w*v.w;
        mx = fmaxf(mx, fmaxf(fmaxf(v.x, v.y), fmaxf(v.z, v.w)));
    }
    __shared__ double ds[256], ds2[256];
    __shared__ float dm[256];
    ds[threadIdx.x] = s; ds2[threadIdx.x] = s2; dm[threadIdx.x] = mx;
    __syncthreads();
    for (int o = 128; o > 0; o >>= 1) {
        if (threadIdx.x < o) {
            ds[threadIdx.x]  += ds[threadIdx.x + o];
            ds2[threadIdx.x] += ds2[threadIdx.x + o];
            dm[threadIdx.x]   = fmaxf(dm[threadIdx.x], dm[threadIdx.x + o]);
        }
        __syncthreads();
    }
    __shared__ float sh_scale, sh_mxs;
    if (threadIdx.x == 0) {
        double mean_num = ds[0];
        double var = (ds2[0] - mean_num*mean_num/(double)VV) / (double)(VV - 1);
        if (var < 0) var = 0;
        float sd = (float)sqrt(var);
        float sc = 1.0f / fmaxf(sd, 1e-6f);
        sh_scale = sc; sh_mxs = dm[0] * sc;
    }
    __syncthreads();
    float sc = sh_scale, mxs = sh_mxs;
    float se = 0.f;
    for (int q = threadIdx.x; q < VV/4; q += 256) {
        float4 v = x4[q];
        se += expf(v.x*sc - mxs) + expf(v.y*sc - mxs) + expf(v.z*sc - mxs) + expf(v.w*sc - mxs);
    }
    __shared__ float fred[256];
    fred[threadIdx.x] = se;
    __syncthreads();
    for (int o = 128; o > 0; o >>= 1) {
        if (threadIdx.x < o) fred[threadIdx.x] += fred[threadIdx.x + o];
        __syncthreads();
    }
    if (threadIdx.x == 0) {
        stp[0] = sc; stp[1] = mxs; stp[2] = 1.0f / fred[0]; stp[3] = (float)idx;
    }
}

// ------------------------------------------------------------ column sums
__global__ void colsum_k(const float* sl, const float* tl, float* ws) {
    int chunk = blockIdx.x, grp = blockIdx.y, t = blockIdx.z;
    int v0 = chunk * 256 + threadIdx.x;
    const float* base = (t == 0) ? sl : tl;
    const float* stats = ws + WS_STATS + (size_t)t * NR * 4 + (size_t)grp * RPG * 4;
    __shared__ float sst[RPG * 4];
    for (int q = threadIdx.x; q < RPG * 4; q += 256) sst[q] = stats[q];
    __syncthreads();
    int b = grp;  // RPG == ANS: each group is exactly one batch row
    const float* bbase = base + (size_t)b * TT_ * VV + v0;
    float acc = 0.f;
    #pragma unroll 4
    for (int rr = 0; rr < RPG; rr++) {
        float idxf = sst[rr*4 + 3];
        if (idxf < 0.f) continue;
        int idx = (int)idxf;
        float xv = bbase[(size_t)idx * VV];
        acc += expf(xv * sst[rr*4 + 0] - sst[rr*4 + 1]) * sst[rr*4 + 2];
    }
    ws[WS_CPART + (size_t)(t*NGRP + grp) * VV + v0] = acc;
}

// ------------------------------------------------------------------ top-k
__global__ void topk_k(float* ws) {
    int t = blockIdx.x;
    const float* cpart = ws + WS_CPART + (size_t)t * NGRP * VV;
    int tid = threadIdx.x;           // 1024 threads
    float lv[32];
    #pragma unroll
    for (int i = 0; i < 32; i++) {
        int v = tid + i * 1024;
        float s = -INFINITY;
        if (v < VV)
            s = cpart[v] + cpart[VV + v] + cpart[2*VV + v] + cpart[3*VV + v];
        lv[i] = s;
    }
    int* order = (int*)(ws + WS_ORDER) + t * 64;
    __shared__ unsigned long long wred[16];
    __shared__ unsigned long long winner;
    int lane = tid & 63, wv = tid >> 6;
    for (int k = 0; k < TOPK; k++) {
        float bv = -INFINITY; int bi = -1;
        #pragma unroll
        for (int i = 0; i < 32; i++) {
            int v = tid + i * 1024;
            if (lv[i] > bv) { bv = lv[i]; bi = v; }
        }
        unsigned long long key = 0ull;
        if (bi >= 0 && bv > -INFINITY)
            key = (((unsigned long long)__float_as_uint(bv)) << 32)
                | (unsigned long long)(0xFFFFFFFFu - (unsigned)bi);
        for (int o = 32; o > 0; o >>= 1) {
            unsigned long long other = __shfl_down(key, o, 64);
            if (other > key) key = other;
        }
        if (lane == 0) wred[wv] = key;
        __syncthreads();
        if (tid == 0) {
            unsigned long long wk = wred[0];
            for (int q = 1; q < 16; q++) if (wred[q] > wk) wk = wred[q];
            winner = wk;
            order[k] = (int)(0xFFFFFFFFu - (unsigned)(wk & 0xFFFFFFFFull));
        }
        __syncthreads();
        unsigned long long wk = winner;
        int widx = (int)(0xFFFFFFFFu - (unsigned)(wk & 0xFFFFFFFFull));
        if ((widx & 1023) == tid) {
            int ii = widx >> 10;
            #pragma unroll
            for (int q = 0; q < 32; q++) if (q == ii) lv[q] = -INFINITY;
        }
        __syncthreads();
    }
}

// --------------------------------------- gather top-50 + second softmax
__global__ void gather_k(const float* sl, const float* tl, float* ws) {
    int gid = blockIdx.x;
    int t = gid >> 11, r = gid & (NR - 1);
    int b = r >> 9, pos = r & (ANS - 1);
    const float* stp = ws + WS_STATS + (size_t)(t*NR + r) * 4;
    int lane = threadIdx.x;          // 64 threads
    float scale = stp[0], mxs = stp[1], invS = stp[2], idxf = stp[3];
    const int* order = (const int*)(ws + WS_ORDER) + t * 64;
    float g = 0.f;
    if (idxf >= 0.f && lane < TOPK) {
        int idx = (int)idxf;
        int c = order[lane];
        float xv = (t == 0 ? sl : tl)[((size_t)b*TT_ + idx) * (size_t)VV + c];
        g = expf(xv * scale - mxs) * invS;
    }
    float z = (lane < TOPK) ? g * 0.5f : -INFINITY;   // /SINK_T, SINK_T=2
    float m = z;
    for (int o = 32; o > 0; o >>= 1) m = fmaxf(m, __shfl_xor(m, o, 64));
    float e = (lane < TOPK) ? expf(z - m) : 0.f;
    float ssum = e;
    for (int o = 32; o > 0; o >>= 1) ssum += __shfl_xor(ssum, o, 64);
    if (lane < TOPK)
        ws[WS_GAT + ((size_t)(t*BB + b)*ANS + pos) * TOPK + lane] = e / ssum;
}

// ------------------------------------------------ W (L1 cost) and K=exp
__global__ void wk_k(float* ws) {
    int bi = blockIdx.x;             // [0, B*ANS)
    int b = bi >> 9, i = bi & (ANS - 1);
    const float* ps  = ws + WS_GAT + ((size_t)b*ANS + i) * TOPK;            // student t=0
    const float* ptb = ws + WS_GAT + ((size_t)(BB + b)*ANS) * TOPK;         // teacher t=1
    __shared__ float sps[TOPK];
    if (threadIdx.x < TOPK) sps[threadIdx.x] = ps[threadIdx.x];
    __syncthreads();
    for (int j = threadIdx.x; j < ANS; j += 256) {
        const float* pt = ptb + (size_t)j * TOPK;
        float w = 0.f;
        #pragma unroll
        for (int k2 = 0; k2 < TOPK; k2++) w += fabsf(sps[k2] - pt[k2]);
        size_t off = ((size_t)b*ANS + i) * ANS + j;
        ws[WS_W + off] = w;
        ws[WS_K + off] = fmaxf(expf(-2.0f * w), 1e-30f);   // exp(-W/eps), eps=0.5
    }
    if (i == 0) {
        for (int q = threadIdx.x; q < ANS; q += 256) {
            ws[WS_U + b*ANS + q] = 1.0f;
            ws[WS_V + b*ANS + q] = 1.0f;
        }
    }
}

// ------------------------------------------- Sinkhorn in u/v scaling form
__global__ void rownorm_k(float* ws) {
    int wave = threadIdx.x >> 6, lane = threadIdx.x & 63;
    int row = blockIdx.x * 4 + wave;            // [0, 2048)
    int b = row >> 9, i = row & (ANS - 1);
    const float* Krow = ws + WS_K + ((size_t)b*ANS + i) * ANS;
    const float* v = ws + WS_V + b*ANS;
    float acc = 0.f;
    #pragma unroll
    for (int c = lane; c < ANS; c += 64) acc += Krow[c] * v[c];
    for (int o = 32; o > 0; o >>= 1) acc += __shfl_xor(acc, o, 64);
    if (lane == 0) {
        float* u = ws + WS_U + b*ANS;
        float ui = u[i];
        u[i] = ui / fmaxf(ui * acc, 1e-10f);
    }
}

__global__ void colnorm_k(float* ws) {
    int b = blockIdx.x >> 3, g = blockIdx.x & 7;
    int jj = threadIdx.x & 63, ii = threadIdx.x >> 6;   // ii in [0,4)
    int j = g * 64 + jj;
    const float* K = ws + WS_K + (size_t)b*ANS*ANS;
    const float* u = ws + WS_U + b*ANS;
    float acc = 0.f;
    #pragma unroll 4
    for (int i = ii; i < ANS; i += 4) acc += K[(size_t)i*ANS + j] * u[i];
    __shared__ float part[4][64];
    part[ii][jj] = acc;
    __syncthreads();
    if (ii == 0) {
        float s = part[0][jj] + part[1][jj] + part[2][jj] + part[3][jj];
        float* v = ws + WS_V + b*ANS;
        float vj = v[j];
        v[j] = vj / fmaxf(vj * s, 1e-10f);
    }
}

// ------------------------------------------------------- sum(P*W) + total
__global__ void wsum_k(float* ws) {
    int b = blockIdx.x >> 3, sl = blockIdx.x & 7;
    const float* K = ws + WS_K + (size_t)b*ANS*ANS;
    const float* W = ws + WS_W + (size_t)b*ANS*ANS;
    const float* u = ws + WS_U + b*ANS;
    const float* v = ws + WS_V + b*ANS;
    float acc = 0.f;
    const int n = ANS*ANS/8;   // 32768
    int base = sl * n;
    for (int q = threadIdx.x; q < n; q += 256) {
        int idx = base + q;
        int i = idx >> 9, j = idx & (ANS - 1);
        acc += u[i] * K[idx] * v[j] * W[idx];
    }
    __shared__ float red[256];
    red[threadIdx.x] = acc;
    __syncthreads();
    for (int o = 128; o > 0; o >>= 1) {
        if (threadIdx.x < o) red[threadIdx.x] += red[threadIdx.x + o];
        __syncthreads();
    }
    if (threadIdx.x == 0) ws[WS_LOSSP + blockIdx.x] = red[0];
}

__global__ void finalize_k(const float* ce, float* ws, float* out) {
    if (threadIdx.x == 0) {
        float s = 0.f;
        for (int q = 0; q < 32; q++) s += ws[WS_LOSSP + q];
        out[0] = ce[0] + 0.001f * s;
    }
}

// ---------------------------------------------------------------- launch
extern "C" void kernel_launch(void* const* d_in, const int* in_sizes, int n_in,
                              void* d_out, int out_size, void* d_ws, size_t ws_size,
                              hipStream_t stream) {
    const float* sl = (const float*)d_in[0];
    const float* tl = (const float*)d_in[1];
    const float* ce = (const float*)d_in[2];
    const int*   st = (const int*)d_in[3];
    const int*   tt = (const int*)d_in[4];
    float* ws = (float*)d_ws;
    float* out = (float*)d_out;

    hipLaunchKernelGGL(answers_k,  dim3(8),                 dim3(256),  0, stream, st, tt, ws);
    hipLaunchKernelGGL(rowstats_k, dim3(2*NR),              dim3(256),  0, stream, sl, tl, ws);
    hipLaunchKernelGGL(colsum_k,   dim3(NCHUNK, NGRP, 2),   dim3(256),  0, stream, sl, tl, ws);
    hipLaunchKernelGGL(topk_k,     dim3(2),                 dim3(1024), 0, stream, ws);
    hipLaunchKernelGGL(gather_k,   dim3(2*NR),              dim3(64),   0, stream, sl, tl, ws);
    hipLaunchKernelGGL(wk_k,       dim3(BB*ANS),            dim3(256),  0, stream, ws);
    for (int it = 0; it < 10; it++) {
        hipLaunchKernelGGL(rownorm_k, dim3(NR/4), dim3(256), 0, stream, ws);
        hipLaunchKernelGGL(colnorm_k, dim3(32),   dim3(256), 0, stream, ws);
    }
    hipLaunchKernelGGL(wsum_k,     dim3(32), dim3(256), 0, stream, ws);
    hipLaunchKernelGGL(finalize_k, dim3(1),  dim3(64),  0, stream, ce, ws, out);
}